// Round 20
// baseline (768.463 us; speedup 1.0000x reference)
//
#include <hip/hip_runtime.h>

typedef float    f32x4 __attribute__((ext_vector_type(4)));
typedef _Float16 h8    __attribute__((ext_vector_type(8)));
typedef unsigned int uint;
typedef unsigned short ushort;

#define NT    512
#define SEQN  12
#define ROWS  64

// ws offsets (in 4-byte units)
#define OFF_PART   0          // [512][2][96] BN partials
#define OFF_SCALE  98304      // [96]
#define OFF_SHIFT  98400      // [96]
#define OFF_WG     98496      // 204800 u32: [kt10][half2][nq4][t10][lane64][4u32] (fp16)
#define OFF_WA     303296     // 33280 u32:  [s13][kt10][lane64][4u32] (fp16)

#define WG_U32     204800
#define WA_U32     33280

// LDS layout (bytes)
#define L_HH    0          // [64][320] ushort fp16, swizzled (40960)
#define L_B     40960      // 2 x 40960 staged B ring (81920)
#define L_XG    122880     // [64][96] f32 (24576)
#define L_Q     147456     // [64][12] f32 (3072)
#define L_TA    150528     // [64][12] f32 (3072)
#define L_SCS   153600     // [96] f32
#define L_SHS   153984     // [96] f32
#define L_WSA   154368     // [8][8] f32
#define L_BSA   154624     // [8] f32
#define SMEM_BYTES 154656
// phase-1 overlays: Win [96][97] f32 (37248) at byte 0 (inside h region);
// xn [64][96] f32 (24576) at L_B

__device__ __forceinline__ float sigm_(float v) { return 1.f / (1.f + __expf(-v)); }
__device__ __forceinline__ float tanh_(float v) { float e = __expf(2.f * v); return 1.f - 2.f / (e + 1.f); }

__device__ __forceinline__ ushort f2h_bits(float v) {
    _Float16 h = (_Float16)v;        // RTN convert
    ushort b;
    __builtin_memcpy(&b, &h, 2);
    return b;
}
// swizzled byte offset into h array ([64][320] ushort)
__device__ __forceinline__ int haddr(int row, int u) {
    return ((row * 640 + u * 2) ^ ((row & 7) << 4));
}

__device__ __forceinline__ void gload_lds16(const void* src, void* dst) {
    __builtin_amdgcn_global_load_lds((const __attribute__((address_space(1))) void*)src,
                                     (__attribute__((address_space(3))) void*)dst, 16, 0, 0);
}

// ---------------- Kernel 1: BN partial sums ----------------
__global__ __launch_bounds__(192) void bn_partial_k(const float* __restrict__ x,
                                                    float* __restrict__ ws) {
    __shared__ float sm[2][2][96];
    int t = threadIdx.x;
    int half = t / 96, f = t - half * 96;
    int r0 = blockIdx.x * 64 + half * 32;
    float s1 = 0.f, s2 = 0.f;
    for (int r = 0; r < 32; ++r) {
        float v = x[(size_t)(r0 + r) * 96 + f];
        s1 += v; s2 += v * v;
    }
    sm[half][0][f] = s1; sm[half][1][f] = s2;
    __syncthreads();
    if (t < 96) {
        ws[OFF_PART + blockIdx.x * 192 + t]      = sm[0][0][t] + sm[1][0][t];
        ws[OFF_PART + blockIdx.x * 192 + 96 + t] = sm[0][1][t] + sm[1][1][t];
    }
}

// ---------------- Kernel 2: build fp16 fragment tables ----------------
// tile (0..79): nq = tile/20, rem = tile%20, us = rem/4, g = rem%4
__device__ __forceinline__ float wg_val(int kt, int tile, int lane, int e,
                                        const float* W_hh, const float* W_ih,
                                        const float* b_ih, const float* b_hh) {
    int nq = tile / 20, rem = tile % 20;
    int us = rem / 4, g = rem & 3;
    int u = nq * 80 + us * 16 + (lane & 15);
    int k = kt * 32 + ((lane >> 4) << 3) + e;
    if (u >= 300) return 0.f;
    int gu = g * 300 + u;
    if (k < 300)  return W_hh[(size_t)gu * 300 + k];
    if (k == 300) return b_ih[gu] + b_hh[gu];
    if (k >= 312) return W_ih[gu * 8 + (k - 312)];
    return 0.f;
}
__device__ __forceinline__ float wa_val(int s, int kt, int lane, int e,
                                        const float* W_ta, const float* W_out) {
    if (s == 0) return 0.f;
    int u = lane & 15;
    int k = kt * 32 + ((lane >> 4) << 3) + e;
    if (k >= 300 || u > 12) return 0.f;
    if (u < 12) return W_ta[(size_t)u * 3600 + (s - 1) * 300 + k];
    return W_out[k];
}

__global__ __launch_bounds__(256) void prep_k(const float* __restrict__ bn_gamma,
                                              const float* __restrict__ bn_beta,
                                              const float* __restrict__ W_ih,
                                              const float* __restrict__ b_ih,
                                              const float* __restrict__ W_hh,
                                              const float* __restrict__ b_hh,
                                              const float* __restrict__ W_ta,
                                              const float* __restrict__ W_out,
                                              float* __restrict__ ws) {
    int idx = blockIdx.x * 256 + threadIdx.x;
    uint* wsu = (uint*)ws;
    if (idx < WG_U32) {
        // layout: [kt10][half2][nq4][t10][lane64][4u32]
        int word  = idx & 3;
        int lane  = (idx >> 2) & 63;
        int rest  = idx >> 8;          // 0..799
        int t     = rest % 10;
        int rest2 = rest / 10;         // 0..79
        int nq    = rest2 % 4;
        int rest3 = rest2 / 4;         // 0..19
        int half  = rest3 & 1;
        int kt    = rest3 >> 1;
        int tile  = nq * 20 + half * 10 + t;
        int e0 = word * 2;
        float v0 = wg_val(kt, tile, lane, e0,     W_hh, W_ih, b_ih, b_hh);
        float v1 = wg_val(kt, tile, lane, e0 + 1, W_hh, W_ih, b_ih, b_hh);
        uint b0 = f2h_bits(v0), b1 = f2h_bits(v1);
        wsu[OFF_WG + idx] = b0 | (b1 << 16);
        return;
    }
    int i2 = idx - WG_U32;
    if (i2 < WA_U32) {
        // layout: [s13][kt10][lane64][4u32]
        int word = i2 & 3;
        int lane = (i2 >> 2) & 63;
        int lin  = i2 >> 8;            // 0..129
        int kt   = lin % 10;
        int s    = lin / 10;
        int e0 = word * 2;
        float v0 = wa_val(s, kt, lane, e0,     W_ta, W_out);
        float v1 = wa_val(s, kt, lane, e0 + 1, W_ta, W_out);
        uint b0 = f2h_bits(v0), b1 = f2h_bits(v1);
        wsu[OFF_WA + i2] = b0 | (b1 << 16);
        return;
    }
    int i5 = i2 - WA_U32;
    if (i5 < 96) {
        float s1 = 0.f, s2 = 0.f;
        for (int b = 0; b < 512; ++b) {
            s1 += ws[OFF_PART + b * 192 + i5];
            s2 += ws[OFF_PART + b * 192 + 96 + i5];
        }
        float mu  = s1 * (1.f / 32768.f);
        float var = s2 * (1.f / 32768.f) - mu * mu;
        float rs  = rsqrtf(var + 1e-5f);
        float sc  = bn_gamma[i5] * rs;
        ws[OFF_SCALE + i5] = sc;
        ws[OFF_SHIFT + i5] = bn_beta[i5] - mu * sc;
    }
}

// ---------------- Kernel 3: fused everything (fp16, 40KB half-kt chunks) ----------------
// 64 rows/block, 512 blocks, 8 waves = rh(2) x nq(4); each wave 2 row-tiles x
// 20 col-tiles (acc[40]); one fp16 MFMA per (row-tile, col-tile). B staged via
// global_load_lds in 40KB half-kt chunks (10 tiles/nq), ring-2, counted
// vmcnt(5) + raw barriers — 20 barrier-phases/step (2.5x fewer than r19).
__global__ __launch_bounds__(NT, 2) void mega_k(const float* __restrict__ x,
                                                const float* __restrict__ W_in,
                                                const float* __restrict__ W_sa,
                                                const float* __restrict__ b_sa,
                                                const float* __restrict__ b_ta,
                                                const float* __restrict__ ws,
                                                float* __restrict__ out) {
    extern __shared__ char smc[];
    ushort* h_h   = (ushort*)(smc + L_HH);
    float*  xg    = (float*)(smc + L_XG);
    float*  q_lds = (float*)(smc + L_Q);
    float*  ta_l  = (float*)(smc + L_TA);
    float*  scs   = (float*)(smc + L_SCS);
    float*  shs   = (float*)(smc + L_SHS);
    float*  wsa   = (float*)(smc + L_WSA);
    float*  bsa   = (float*)(smc + L_BSA);
    float*  Win   = (float*)smc;                  // phase-1 overlay [96][97]
    float*  xn    = (float*)(smc + L_B);          // phase-1 overlay [64][96]

    const int tid = threadIdx.x;
    const int gr0 = blockIdx.x * ROWS;

    // ---- phase 1: BN apply + input projection + spatial attention ----
    for (int i = tid; i < 96; i += NT) { scs[i] = ws[OFF_SCALE + i]; shs[i] = ws[OFF_SHIFT + i]; }
    for (int i = tid; i < 64; i += NT) wsa[i] = W_sa[i];
    for (int i = tid; i < 8;  i += NT) bsa[i] = b_sa[i];
    for (int i = tid; i < 96 * 96; i += NT) { int r = i / 96, c = i - r * 96; Win[r * 97 + c] = W_in[i]; }
    __syncthreads();
    for (int i = tid; i < ROWS * 96; i += NT) {
        int c = i % 96;
        xn[i] = x[(size_t)gr0 * 96 + i] * scs[c] + shs[c];
    }
    __syncthreads();
    for (int i = tid; i < ROWS * 96; i += NT) {
        int row = i / 96, col = i - row * 96;
        const float* xr = xn + row * 96;
        const float* wr = Win + col * 97;
        float acc = 0.f;
        #pragma unroll 8
        for (int jj = 0; jj < 96; ++jj) acc += xr[jj] * wr[jj];
        xg[i] = acc;
    }
    __syncthreads();
    for (int p = tid; p < ROWS * SEQN; p += NT) {
        int row = p / 12, s = p - row * 12;
        float* yv = xg + row * 96 + s * 8;
        float y[8], e[8];
        #pragma unroll
        for (int jj = 0; jj < 8; ++jj) y[jj] = yv[jj];
        float mx = -1e30f;
        #pragma unroll
        for (int jj = 0; jj < 8; ++jj) {
            float a = bsa[jj];
            #pragma unroll
            for (int ii = 0; ii < 8; ++ii) a += y[ii] * wsa[jj * 8 + ii];
            a = sigm_(a);
            e[jj] = a; mx = fmaxf(mx, a);
        }
        float den = 0.f;
        #pragma unroll
        for (int jj = 0; jj < 8; ++jj) { e[jj] = __expf(e[jj] - mx); den += e[jj]; }
        float inv = 1.f / den;
        #pragma unroll
        for (int jj = 0; jj < 8; ++jj) yv[jj] = y[jj] * e[jj] * inv;
    }
    __syncthreads();
    // zero h array (retires Win overlay; xn overlay sits in B region)
    for (int i = tid; i < ROWS * 320; i += NT) h_h[i] = 0;
    __syncthreads();
    // bias slot (unit 300 == 1.0 fp16) + xg slots for step 0 (units 312..319)
    for (int r = tid; r < ROWS; r += NT)
        *(ushort*)((char*)h_h + haddr(r, 300)) = 0x3C00;
    {
        int row = tid >> 3, e = tid & 7;
        *(ushort*)((char*)h_h + haddr(row, 312 + e)) = f2h_bits(xg[row * 96 + e]);
    }
    __syncthreads();

    // ---- phase 2: LSTM via fp16 MFMA, pipelined LDS staging ----
    const int wv   = tid >> 6, lane = tid & 63;
    const int rh   = wv >> 2,  nq = wv & 3;
    const int rb   = rh * 32;
    const int a0   = rb + (lane & 15);              // A-row, row-tile 0
    const int a1   = a0 + 16;                       // A-row, row-tile 1
    const int d0   = rb + ((lane >> 4) << 2);       // D rows base, row-tile 0
    const int d1   = d0 + 16;                       // D rows base, row-tile 1
    const int lcol = lane & 15;
    const char* wgb     = (const char*)(ws + OFF_WG);
    const char* wa_lane = (const char*)(ws + OFF_WA) + (size_t)lane * 16;

    // chunk = 40KB = one (kt,half) slice; per wave: 5 staging loads
    #define STAGE(CH, BUF)                                                             \
        {   _Pragma("unroll")                                                          \
            for (int i_ = 0; i_ < 5; ++i_) {                                           \
                const char* s_ = wgb + (size_t)(CH) * 40960 + (wv * 5 + i_) * 1024     \
                                      + (size_t)lane * 16;                             \
                char* d_ = smc + L_B + (BUF) * 40960 + (wv * 5 + i_) * 1024            \
                                + lane * 16;                                           \
                gload_lds16(s_, d_);                                                   \
            }                                                                          \
        }

    f32x4 acc[40];                                  // [rt*20 + us*4 + g]
    f32x4 accA0 = {0.f, 0.f, 0.f, 0.f};
    f32x4 accA1 = {0.f, 0.f, 0.f, 0.f};
    float cst[40];
    #pragma unroll
    for (int t = 0; t < 40; ++t) cst[t] = 0.f;

    STAGE(0, 0);
    asm volatile("s_waitcnt lgkmcnt(0)" ::: "memory");   // h init visible; DMA stays in flight
    __builtin_amdgcn_s_barrier();
    __builtin_amdgcn_sched_barrier(0);

    #pragma unroll 1
    for (int s = 0; s < SEQN; ++s) {
        #pragma unroll
        for (int t = 0; t < 40; ++t) acc[t] = (f32x4){0.f, 0.f, 0.f, 0.f};

        #pragma unroll 1
        for (int kt = 0; kt < 10; ++kt) {
            const int koff = kt * 32 + ((lane >> 4) << 3);
            h8 a0v = *(const h8*)((const char*)h_h + haddr(a0, koff));
            h8 a1v = *(const h8*)((const char*)h_h + haddr(a1, koff));
            #pragma unroll
            for (int hf = 0; hf < 2; ++hf) {
                const int ch = kt * 2 + hf;
                const int cn = (ch == 19) ? 0 : ch + 1;   // wraps across steps (table s-invariant)
                STAGE(cn, cn & 1);
                asm volatile("s_waitcnt vmcnt(5)" ::: "memory");   // my chunk-ch loads landed
                __builtin_amdgcn_s_barrier();                       // everyone's landed
                __builtin_amdgcn_sched_barrier(0);
                const char* bb = smc + L_B + (ch & 1) * 40960 + nq * 10240 + (size_t)lane * 16;
                #pragma unroll
                for (int t = 0; t < 10; ++t) {
                    const int tt = hf * 10 + t;
                    h8 bv = *(const h8*)(bb + t * 1024);
                    acc[tt]      = __builtin_amdgcn_mfma_f32_16x16x32_f16(a0v, bv, acc[tt],      0, 0, 0);
                    acc[20 + tt] = __builtin_amdgcn_mfma_f32_16x16x32_f16(a1v, bv, acc[20 + tt], 0, 0, 0);
                }
            }
        }
        // attention (waves with nq==3), h still h_s here
        if (nq == 3) {
            #pragma unroll 1
            for (int kt = 0; kt < 10; ++kt) {
                const int koff = kt * 32 + ((lane >> 4) << 3);
                h8 a0v = *(const h8*)((const char*)h_h + haddr(a0, koff));
                h8 a1v = *(const h8*)((const char*)h_h + haddr(a1, koff));
                h8 bv  = *(const h8*)(wa_lane + (size_t)(s * 10 + kt) * 1024);
                accA0 = __builtin_amdgcn_mfma_f32_16x16x32_f16(a0v, bv, accA0, 0, 0, 0);
                accA1 = __builtin_amdgcn_mfma_f32_16x16x32_f16(a1v, bv, accA1, 0, 0, 0);
            }
        }
        // all h reads complete before overwrite (LDS-only drain; DMA stays in flight)
        asm volatile("s_waitcnt lgkmcnt(0)" ::: "memory");
        __builtin_amdgcn_s_barrier();
        __builtin_amdgcn_sched_barrier(0);

        // activation + h write (gate g at acc[rt*20+us*4+g], same lane/reg)
        #pragma unroll
        for (int rt = 0; rt < 2; ++rt) {
            const int db = rt ? d1 : d0;
            #pragma unroll
            for (int us = 0; us < 5; ++us) {
                int u = nq * 80 + us * 16 + lcol;
                bool live = (u < 300);
                #pragma unroll
                for (int r = 0; r < 4; ++r) {
                    float iv = sigm_(acc[rt * 20 + us * 4 + 0][r]);
                    float fv = sigm_(acc[rt * 20 + us * 4 + 1][r]);
                    float gv = tanh_(acc[rt * 20 + us * 4 + 2][r]);
                    float ov = sigm_(acc[rt * 20 + us * 4 + 3][r]);
                    float cn = fv * cst[rt * 20 + us * 4 + r] + iv * gv;
                    cst[rt * 20 + us * 4 + r] = cn;
                    float hv = ov * tanh_(cn);
                    if (live) {
                        int row = db + r;
                        *(ushort*)((char*)h_h + haddr(row, u)) = f2h_bits(hv);
                    }
                }
            }
        }
        // q extraction (col 12 of attention tile) + per-step reset
        if (nq == 3 && lcol == 12) {
            #pragma unroll
            for (int r = 0; r < 4; ++r) {
                if (s >= 1) {
                    q_lds[(d0 + r) * 12 + (s - 1)] = accA0[r];
                    q_lds[(d1 + r) * 12 + (s - 1)] = accA1[r];
                }
                accA0[r] = 0.f;
                accA1[r] = 0.f;
            }
        }
        // xg slots for next step
        if (s < SEQN - 1) {
            int row = tid >> 3, e = tid & 7;
            *(ushort*)((char*)h_h + haddr(row, 312 + e)) = f2h_bits(xg[row * 96 + (s + 1) * 8 + e]);
        }
        asm volatile("s_waitcnt lgkmcnt(0)" ::: "memory");
        __builtin_amdgcn_s_barrier();
        __builtin_amdgcn_sched_barrier(0);
    }

    // ---- final attention pass for h_11 (table index s=12) ----
    if (nq == 3) {
        #pragma unroll 1
        for (int kt = 0; kt < 10; ++kt) {
            const int koff = kt * 32 + ((lane >> 4) << 3);
            h8 a0v = *(const h8*)((const char*)h_h + haddr(a0, koff));
            h8 a1v = *(const h8*)((const char*)h_h + haddr(a1, koff));
            h8 bv  = *(const h8*)(wa_lane + (size_t)(12 * 10 + kt) * 1024);
            accA0 = __builtin_amdgcn_mfma_f32_16x16x32_f16(a0v, bv, accA0, 0, 0, 0);
            accA1 = __builtin_amdgcn_mfma_f32_16x16x32_f16(a1v, bv, accA1, 0, 0, 0);
        }
        if (lcol < 12) {
            #pragma unroll
            for (int r = 0; r < 4; ++r) {
                ta_l[(d0 + r) * 12 + lcol] = accA0[r];
                ta_l[(d1 + r) * 12 + lcol] = accA1[r];
            }
        } else if (lcol == 12) {
            #pragma unroll
            for (int r = 0; r < 4; ++r) {
                q_lds[(d0 + r) * 12 + 11] = accA0[r];
                q_lds[(d1 + r) * 12 + 11] = accA1[r];
            }
        }
    }
    __syncthreads();

    // ---- phase 3: softmax(relu(ta + b_ta)) and output ----
    if (tid < ROWS) {
        float l[12]; float mx = 0.f;
        #pragma unroll
        for (int s2 = 0; s2 < 12; ++s2) {
            float v = fmaxf(ta_l[tid * 12 + s2] + b_ta[s2], 0.f);
            l[s2] = v; mx = fmaxf(mx, v);
        }
        float den = 0.f, o = 0.f;
        #pragma unroll
        for (int s2 = 0; s2 < 12; ++s2) {
            float e = __expf(l[s2] - mx);
            den += e; o += e * q_lds[tid * 12 + s2];
        }
        out[gr0 + tid] = o / den;
    }
    #undef STAGE
}

extern "C" void kernel_launch(void* const* d_in, const int* in_sizes, int n_in,
                              void* d_out, int out_size, void* d_ws, size_t ws_size,
                              hipStream_t stream) {
    const float* x        = (const float*)d_in[0];
    const float* bn_gamma = (const float*)d_in[1];
    const float* bn_beta  = (const float*)d_in[2];
    const float* W_in     = (const float*)d_in[3];
    const float* W_sa     = (const float*)d_in[4];
    const float* b_sa     = (const float*)d_in[5];
    const float* W_ih     = (const float*)d_in[6];
    const float* b_ih     = (const float*)d_in[7];
    const float* W_hh     = (const float*)d_in[8];
    const float* b_hh     = (const float*)d_in[9];
    const float* W_ta     = (const float*)d_in[10];
    const float* b_ta     = (const float*)d_in[11];
    const float* W_out    = (const float*)d_in[12];
    float* ws  = (float*)d_ws;
    float* out = (float*)d_out;

    (void)in_sizes; (void)n_in; (void)out_size; (void)ws_size;

    (void)hipFuncSetAttribute((const void*)mega_k,
                              hipFuncAttributeMaxDynamicSharedMemorySize, SMEM_BYTES);

    bn_partial_k<<<512, 192, 0, stream>>>(x, ws);
    int prep_items = WG_U32 + WA_U32 + 96;
    prep_k<<<(prep_items + 255) / 256, 256, 0, stream>>>(bn_gamma, bn_beta, W_ih, b_ih,
                                                         W_hh, b_hh, W_ta, W_out, ws);
    mega_k<<<512, NT, SMEM_BYTES, stream>>>(x, W_in, W_sa, b_sa, b_ta, ws, out);
}

// Round 21
// 719.091 us; speedup vs baseline: 1.0687x; 1.0687x over previous
//
#include <hip/hip_runtime.h>

typedef float    f32x4 __attribute__((ext_vector_type(4)));
typedef _Float16 h8    __attribute__((ext_vector_type(8)));
typedef unsigned int uint;
typedef unsigned short ushort;

#define NT    512
#define SEQN  12
#define ROWS  64

// ws offsets (in 4-byte units)
#define OFF_PART   0          // [512][2][96] BN partials
#define OFF_SCALE  98304      // [96]
#define OFF_SHIFT  98400      // [96]
#define OFF_WG     98496      // 204800 u32: [q50][nq4][j4][lane64][4u32]; q=kt*5+c4 (fp16)
#define OFF_WA     303296     // 33280 u32:  [s13][kt10][lane64][4u32] (fp16)

#define WG_U32     204800
#define WA_U32     33280

// LDS layout (bytes)
#define L_HH    0          // [64][320] ushort fp16, swizzled (40960)
#define L_B     40960      // 4 x 16384 staged B ring (65536)
#define L_XG    106496     // [64][96] f32 (24576)
#define L_Q     131072     // [64][12] f32 (3072)
#define L_TA    134144     // [64][12] f32 (3072)
#define L_SCS   137216     // [96] f32
#define L_SHS   137600     // [96] f32
#define L_WSA   137984     // [8][8] f32
#define L_BSA   138240     // [8] f32
#define SMEM_BYTES 138272
// phase-1 overlays: Win [96][97] f32 (37248) at byte 0 (inside h region);
// xn [64][96] f32 (24576) at L_B

__device__ __forceinline__ float sigm_(float v) { return 1.f / (1.f + __expf(-v)); }
__device__ __forceinline__ float tanh_(float v) { float e = __expf(2.f * v); return 1.f - 2.f / (e + 1.f); }

__device__ __forceinline__ ushort f2h_bits(float v) {
    _Float16 h = (_Float16)v;        // RTN convert
    ushort b;
    __builtin_memcpy(&b, &h, 2);
    return b;
}
// swizzled byte offset into h array ([64][320] ushort)
__device__ __forceinline__ int haddr(int row, int u) {
    return ((row * 640 + u * 2) ^ ((row & 7) << 4));
}

__device__ __forceinline__ void gload_lds16(const void* src, void* dst) {
    __builtin_amdgcn_global_load_lds((const __attribute__((address_space(1))) void*)src,
                                     (__attribute__((address_space(3))) void*)dst, 16, 0, 0);
}

// ---------------- Kernel 1: BN partial sums ----------------
__global__ __launch_bounds__(192) void bn_partial_k(const float* __restrict__ x,
                                                    float* __restrict__ ws) {
    __shared__ float sm[2][2][96];
    int t = threadIdx.x;
    int half = t / 96, f = t - half * 96;
    int r0 = blockIdx.x * 64 + half * 32;
    float s1 = 0.f, s2 = 0.f;
    for (int r = 0; r < 32; ++r) {
        float v = x[(size_t)(r0 + r) * 96 + f];
        s1 += v; s2 += v * v;
    }
    sm[half][0][f] = s1; sm[half][1][f] = s2;
    __syncthreads();
    if (t < 96) {
        ws[OFF_PART + blockIdx.x * 192 + t]      = sm[0][0][t] + sm[1][0][t];
        ws[OFF_PART + blockIdx.x * 192 + 96 + t] = sm[0][1][t] + sm[1][1][t];
    }
}

// ---------------- Kernel 2: build fp16 fragment tables ----------------
// tile (0..79): nq = tile/20, rem = tile%20, us = rem/4, g = rem%4
__device__ __forceinline__ float wg_val(int kt, int tile, int lane, int e,
                                        const float* W_hh, const float* W_ih,
                                        const float* b_ih, const float* b_hh) {
    int nq = tile / 20, rem = tile % 20;
    int us = rem / 4, g = rem & 3;
    int u = nq * 80 + us * 16 + (lane & 15);
    int k = kt * 32 + ((lane >> 4) << 3) + e;
    if (u >= 300) return 0.f;
    int gu = g * 300 + u;
    if (k < 300)  return W_hh[(size_t)gu * 300 + k];
    if (k == 300) return b_ih[gu] + b_hh[gu];
    if (k >= 312) return W_ih[gu * 8 + (k - 312)];
    return 0.f;
}
__device__ __forceinline__ float wa_val(int s, int kt, int lane, int e,
                                        const float* W_ta, const float* W_out) {
    if (s == 0) return 0.f;
    int u = lane & 15;
    int k = kt * 32 + ((lane >> 4) << 3) + e;
    if (k >= 300 || u > 12) return 0.f;
    if (u < 12) return W_ta[(size_t)u * 3600 + (s - 1) * 300 + k];
    return W_out[k];
}

__global__ __launch_bounds__(256) void prep_k(const float* __restrict__ bn_gamma,
                                              const float* __restrict__ bn_beta,
                                              const float* __restrict__ W_ih,
                                              const float* __restrict__ b_ih,
                                              const float* __restrict__ W_hh,
                                              const float* __restrict__ b_hh,
                                              const float* __restrict__ W_ta,
                                              const float* __restrict__ W_out,
                                              float* __restrict__ ws) {
    int idx = blockIdx.x * 256 + threadIdx.x;
    uint* wsu = (uint*)ws;
    if (idx < WG_U32) {
        // layout: [q50][nq4][j4][lane64][4u32]
        int word = idx & 3;
        int lane = (idx >> 2) & 63;
        int j    = (idx >> 8) & 3;
        int nq   = (idx >> 10) & 3;
        int q    = idx >> 12;          // 0..49
        int kt   = q / 5, c4 = q % 5;
        int tile = nq * 20 + c4 * 4 + j;
        int e0 = word * 2;
        float v0 = wg_val(kt, tile, lane, e0,     W_hh, W_ih, b_ih, b_hh);
        float v1 = wg_val(kt, tile, lane, e0 + 1, W_hh, W_ih, b_ih, b_hh);
        uint b0 = f2h_bits(v0), b1 = f2h_bits(v1);
        wsu[OFF_WG + idx] = b0 | (b1 << 16);
        return;
    }
    int i2 = idx - WG_U32;
    if (i2 < WA_U32) {
        // layout: [s13][kt10][lane64][4u32]
        int word = i2 & 3;
        int lane = (i2 >> 2) & 63;
        int lin  = i2 >> 8;            // 0..129
        int kt   = lin % 10;
        int s    = lin / 10;
        int e0 = word * 2;
        float v0 = wa_val(s, kt, lane, e0,     W_ta, W_out);
        float v1 = wa_val(s, kt, lane, e0 + 1, W_ta, W_out);
        uint b0 = f2h_bits(v0), b1 = f2h_bits(v1);
        wsu[OFF_WA + i2] = b0 | (b1 << 16);
        return;
    }
    int i5 = i2 - WA_U32;
    if (i5 < 96) {
        float s1 = 0.f, s2 = 0.f;
        for (int b = 0; b < 512; ++b) {
            s1 += ws[OFF_PART + b * 192 + i5];
            s2 += ws[OFF_PART + b * 192 + 96 + i5];
        }
        float mu  = s1 * (1.f / 32768.f);
        float var = s2 * (1.f / 32768.f) - mu * mu;
        float rs  = rsqrtf(var + 1e-5f);
        float sc  = bn_gamma[i5] * rs;
        ws[OFF_SCALE + i5] = sc;
        ws[OFF_SHIFT + i5] = bn_beta[i5] - mu * sc;
    }
}

// ---------------- Kernel 3: fused everything (fp16, ring-4 lead-2) ----------------
// 64 rows/block, 512 blocks, 8 waves = rh(2) x nq(4); each wave 2 row-tiles x
// 20 col-tiles (acc[40]); one fp16 MFMA per (row-tile, col-tile). B staged via
// global_load_lds in 16KB chunks, ring-4, staged TWO phases ahead:
// phase q stages chunk q+2 into buf (sb+q+2)&3 — that buffer's last readers
// (chunk q-2, phase q-2) are separated by barrier q-1 => race-free, and the
// DMA has ~2 phase-times to land before its consumer's vmcnt(4).
__global__ __launch_bounds__(NT, 2) void mega_k(const float* __restrict__ x,
                                                const float* __restrict__ W_in,
                                                const float* __restrict__ W_sa,
                                                const float* __restrict__ b_sa,
                                                const float* __restrict__ b_ta,
                                                const float* __restrict__ ws,
                                                float* __restrict__ out) {
    extern __shared__ char smc[];
    ushort* h_h   = (ushort*)(smc + L_HH);
    float*  xg    = (float*)(smc + L_XG);
    float*  q_lds = (float*)(smc + L_Q);
    float*  ta_l  = (float*)(smc + L_TA);
    float*  scs   = (float*)(smc + L_SCS);
    float*  shs   = (float*)(smc + L_SHS);
    float*  wsa   = (float*)(smc + L_WSA);
    float*  bsa   = (float*)(smc + L_BSA);
    float*  Win   = (float*)smc;                  // phase-1 overlay [96][97]
    float*  xn    = (float*)(smc + L_B);          // phase-1 overlay [64][96]

    const int tid = threadIdx.x;
    const int gr0 = blockIdx.x * ROWS;

    // ---- phase 1: BN apply + input projection + spatial attention ----
    for (int i = tid; i < 96; i += NT) { scs[i] = ws[OFF_SCALE + i]; shs[i] = ws[OFF_SHIFT + i]; }
    for (int i = tid; i < 64; i += NT) wsa[i] = W_sa[i];
    for (int i = tid; i < 8;  i += NT) bsa[i] = b_sa[i];
    for (int i = tid; i < 96 * 96; i += NT) { int r = i / 96, c = i - r * 96; Win[r * 97 + c] = W_in[i]; }
    __syncthreads();
    for (int i = tid; i < ROWS * 96; i += NT) {
        int c = i % 96;
        xn[i] = x[(size_t)gr0 * 96 + i] * scs[c] + shs[c];
    }
    __syncthreads();
    for (int i = tid; i < ROWS * 96; i += NT) {
        int row = i / 96, col = i - row * 96;
        const float* xr = xn + row * 96;
        const float* wr = Win + col * 97;
        float acc = 0.f;
        #pragma unroll 8
        for (int jj = 0; jj < 96; ++jj) acc += xr[jj] * wr[jj];
        xg[i] = acc;
    }
    __syncthreads();
    for (int p = tid; p < ROWS * SEQN; p += NT) {
        int row = p / 12, s = p - row * 12;
        float* yv = xg + row * 96 + s * 8;
        float y[8], e[8];
        #pragma unroll
        for (int jj = 0; jj < 8; ++jj) y[jj] = yv[jj];
        float mx = -1e30f;
        #pragma unroll
        for (int jj = 0; jj < 8; ++jj) {
            float a = bsa[jj];
            #pragma unroll
            for (int ii = 0; ii < 8; ++ii) a += y[ii] * wsa[jj * 8 + ii];
            a = sigm_(a);
            e[jj] = a; mx = fmaxf(mx, a);
        }
        float den = 0.f;
        #pragma unroll
        for (int jj = 0; jj < 8; ++jj) { e[jj] = __expf(e[jj] - mx); den += e[jj]; }
        float inv = 1.f / den;
        #pragma unroll
        for (int jj = 0; jj < 8; ++jj) yv[jj] = y[jj] * e[jj] * inv;
    }
    __syncthreads();
    // zero h array (retires Win overlay; xn overlay sits in B region)
    for (int i = tid; i < ROWS * 320; i += NT) h_h[i] = 0;
    __syncthreads();
    // bias slot (unit 300 == 1.0 fp16) + xg slots for step 0 (units 312..319)
    for (int r = tid; r < ROWS; r += NT)
        *(ushort*)((char*)h_h + haddr(r, 300)) = 0x3C00;
    {
        int row = tid >> 3, e = tid & 7;
        *(ushort*)((char*)h_h + haddr(row, 312 + e)) = f2h_bits(xg[row * 96 + e]);
    }
    __syncthreads();

    // ---- phase 2: LSTM via fp16 MFMA, ring-4 lead-2 LDS staging ----
    const int wv   = tid >> 6, lane = tid & 63;
    const int rh   = wv >> 2,  nq = wv & 3;
    const int rb   = rh * 32;
    const int a0   = rb + (lane & 15);              // A-row, row-tile 0
    const int a1   = a0 + 16;                       // A-row, row-tile 1
    const int d0   = rb + ((lane >> 4) << 2);       // D rows base, row-tile 0
    const int d1   = d0 + 16;                       // D rows base, row-tile 1
    const int lcol = lane & 15;
    const char* wgb     = (const char*)(ws + OFF_WG);
    const char* wa_lane = (const char*)(ws + OFF_WA) + (size_t)lane * 16;

    // chunk = 16KB = one (kt,c4) slice; per wave: 2 staging loads
    #define STAGE(Q, BUF)                                                              \
        {   _Pragma("unroll")                                                          \
            for (int i_ = 0; i_ < 2; ++i_) {                                           \
                const char* s_ = wgb + (size_t)(Q) * 16384 + (wv * 2 + i_) * 1024      \
                                      + (size_t)lane * 16;                             \
                char* d_ = smc + L_B + (BUF) * 16384 + (wv * 2 + i_) * 1024            \
                                + lane * 16;                                           \
                gload_lds16(s_, d_);                                                   \
            }                                                                          \
        }

    f32x4 acc[40];                                  // [rt*20 + us*4 + g]
    f32x4 accA0 = {0.f, 0.f, 0.f, 0.f};
    f32x4 accA1 = {0.f, 0.f, 0.f, 0.f};
    float cst[40];
    #pragma unroll
    for (int t = 0; t < 40; ++t) cst[t] = 0.f;

    STAGE(0, 0);
    STAGE(1, 1);
    asm volatile("s_waitcnt lgkmcnt(0)" ::: "memory");   // h init visible; DMA stays in flight
    __builtin_amdgcn_s_barrier();
    __builtin_amdgcn_sched_barrier(0);

    #pragma unroll 1
    for (int s = 0; s < SEQN; ++s) {
        const int sb = (2 * s) & 3;                  // 50 phases/step => parity shifts by 2
        #pragma unroll
        for (int t = 0; t < 40; ++t) acc[t] = (f32x4){0.f, 0.f, 0.f, 0.f};

        #pragma unroll 1
        for (int kt = 0; kt < 10; ++kt) {
            const int koff = kt * 32 + ((lane >> 4) << 3);
            h8 a0v = *(const h8*)((const char*)h_h + haddr(a0, koff));
            h8 a1v = *(const h8*)((const char*)h_h + haddr(a1, koff));
            #pragma unroll
            for (int c4 = 0; c4 < 5; ++c4) {
                const int q  = kt * 5 + c4;
                int qs = q + 2; if (qs >= 50) qs -= 50;   // wraps across steps (table s-invariant)
                STAGE(qs, (sb + q + 2) & 3);
                asm volatile("s_waitcnt vmcnt(4)" ::: "memory");   // chunk q's 2 loads landed
                __builtin_amdgcn_s_barrier();                       // everyone's landed
                __builtin_amdgcn_sched_barrier(0);
                const char* bb = smc + L_B + ((sb + q) & 3) * 16384 + nq * 4096 + (size_t)lane * 16;
                #pragma unroll
                for (int j = 0; j < 4; ++j) {
                    const int tt = c4 * 4 + j;
                    h8 bv = *(const h8*)(bb + j * 1024);
                    acc[tt]      = __builtin_amdgcn_mfma_f32_16x16x32_f16(a0v, bv, acc[tt],      0, 0, 0);
                    acc[20 + tt] = __builtin_amdgcn_mfma_f32_16x16x32_f16(a1v, bv, acc[20 + tt], 0, 0, 0);
                }
            }
        }
        // attention (waves with nq==3), h still h_s here
        if (nq == 3) {
            #pragma unroll 1
            for (int kt = 0; kt < 10; ++kt) {
                const int koff = kt * 32 + ((lane >> 4) << 3);
                h8 a0v = *(const h8*)((const char*)h_h + haddr(a0, koff));
                h8 a1v = *(const h8*)((const char*)h_h + haddr(a1, koff));
                h8 bv  = *(const h8*)(wa_lane + (size_t)(s * 10 + kt) * 1024);
                accA0 = __builtin_amdgcn_mfma_f32_16x16x32_f16(a0v, bv, accA0, 0, 0, 0);
                accA1 = __builtin_amdgcn_mfma_f32_16x16x32_f16(a1v, bv, accA1, 0, 0, 0);
            }
        }
        // all h reads complete before overwrite (LDS-only drain; DMA stays in flight)
        asm volatile("s_waitcnt lgkmcnt(0)" ::: "memory");
        __builtin_amdgcn_s_barrier();
        __builtin_amdgcn_sched_barrier(0);

        // activation + h write (gate g at acc[rt*20+us*4+g], same lane/reg)
        #pragma unroll
        for (int rt = 0; rt < 2; ++rt) {
            const int db = rt ? d1 : d0;
            #pragma unroll
            for (int us = 0; us < 5; ++us) {
                int u = nq * 80 + us * 16 + lcol;
                bool live = (u < 300);
                #pragma unroll
                for (int r = 0; r < 4; ++r) {
                    float iv = sigm_(acc[rt * 20 + us * 4 + 0][r]);
                    float fv = sigm_(acc[rt * 20 + us * 4 + 1][r]);
                    float gv = tanh_(acc[rt * 20 + us * 4 + 2][r]);
                    float ov = sigm_(acc[rt * 20 + us * 4 + 3][r]);
                    float cn = fv * cst[rt * 20 + us * 4 + r] + iv * gv;
                    cst[rt * 20 + us * 4 + r] = cn;
                    float hv = ov * tanh_(cn);
                    if (live) {
                        int row = db + r;
                        *(ushort*)((char*)h_h + haddr(row, u)) = f2h_bits(hv);
                    }
                }
            }
        }
        // q extraction (col 12 of attention tile) + per-step reset
        if (nq == 3 && lcol == 12) {
            #pragma unroll
            for (int r = 0; r < 4; ++r) {
                if (s >= 1) {
                    q_lds[(d0 + r) * 12 + (s - 1)] = accA0[r];
                    q_lds[(d1 + r) * 12 + (s - 1)] = accA1[r];
                }
                accA0[r] = 0.f;
                accA1[r] = 0.f;
            }
        }
        // xg slots for next step
        if (s < SEQN - 1) {
            int row = tid >> 3, e = tid & 7;
            *(ushort*)((char*)h_h + haddr(row, 312 + e)) = f2h_bits(xg[row * 96 + (s + 1) * 8 + e]);
        }
        asm volatile("s_waitcnt lgkmcnt(0)" ::: "memory");
        __builtin_amdgcn_s_barrier();
        __builtin_amdgcn_sched_barrier(0);
    }

    // ---- final attention pass for h_11 (table index s=12) ----
    if (nq == 3) {
        #pragma unroll 1
        for (int kt = 0; kt < 10; ++kt) {
            const int koff = kt * 32 + ((lane >> 4) << 3);
            h8 a0v = *(const h8*)((const char*)h_h + haddr(a0, koff));
            h8 a1v = *(const h8*)((const char*)h_h + haddr(a1, koff));
            h8 bv  = *(const h8*)(wa_lane + (size_t)(12 * 10 + kt) * 1024);
            accA0 = __builtin_amdgcn_mfma_f32_16x16x32_f16(a0v, bv, accA0, 0, 0, 0);
            accA1 = __builtin_amdgcn_mfma_f32_16x16x32_f16(a1v, bv, accA1, 0, 0, 0);
        }
        if (lcol < 12) {
            #pragma unroll
            for (int r = 0; r < 4; ++r) {
                ta_l[(d0 + r) * 12 + lcol] = accA0[r];
                ta_l[(d1 + r) * 12 + lcol] = accA1[r];
            }
        } else if (lcol == 12) {
            #pragma unroll
            for (int r = 0; r < 4; ++r) {
                q_lds[(d0 + r) * 12 + 11] = accA0[r];
                q_lds[(d1 + r) * 12 + 11] = accA1[r];
            }
        }
    }
    __syncthreads();

    // ---- phase 3: softmax(relu(ta + b_ta)) and output ----
    if (tid < ROWS) {
        float l[12]; float mx = 0.f;
        #pragma unroll
        for (int s2 = 0; s2 < 12; ++s2) {
            float v = fmaxf(ta_l[tid * 12 + s2] + b_ta[s2], 0.f);
            l[s2] = v; mx = fmaxf(mx, v);
        }
        float den = 0.f, o = 0.f;
        #pragma unroll
        for (int s2 = 0; s2 < 12; ++s2) {
            float e = __expf(l[s2] - mx);
            den += e; o += e * q_lds[tid * 12 + s2];
        }
        out[gr0 + tid] = o / den;
    }
    #undef STAGE
}

extern "C" void kernel_launch(void* const* d_in, const int* in_sizes, int n_in,
                              void* d_out, int out_size, void* d_ws, size_t ws_size,
                              hipStream_t stream) {
    const float* x        = (const float*)d_in[0];
    const float* bn_gamma = (const float*)d_in[1];
    const float* bn_beta  = (const float*)d_in[2];
    const float* W_in     = (const float*)d_in[3];
    const float* W_sa     = (const float*)d_in[4];
    const float* b_sa     = (const float*)d_in[5];
    const float* W_ih     = (const float*)d_in[6];
    const float* b_ih     = (const float*)d_in[7];
    const float* W_hh     = (const float*)d_in[8];
    const float* b_hh     = (const float*)d_in[9];
    const float* W_ta     = (const float*)d_in[10];
    const float* b_ta     = (const float*)d_in[11];
    const float* W_out    = (const float*)d_in[12];
    float* ws  = (float*)d_ws;
    float* out = (float*)d_out;

    (void)in_sizes; (void)n_in; (void)out_size; (void)ws_size;

    (void)hipFuncSetAttribute((const void*)mega_k,
                              hipFuncAttributeMaxDynamicSharedMemorySize, SMEM_BYTES);

    bn_partial_k<<<512, 192, 0, stream>>>(x, ws);
    int prep_items = WG_U32 + WA_U32 + 96;
    prep_k<<<(prep_items + 255) / 256, 256, 0, stream>>>(bn_gamma, bn_beta, W_ih, b_ih,
                                                         W_hh, b_hh, W_ta, W_out, ws);
    mega_k<<<512, NT, SMEM_BYTES, stream>>>(x, W_in, W_sa, b_sa, b_ta, ws, out);
}